// Round 7
// baseline (371.617 us; speedup 1.0000x reference)
//
#include <hip/hip_runtime.h>

// GCNFast: out[b,s,t,d] = relu( sum_j relu(AA[i%64,j%64]*GCW[i,j]) * X[j,b,d] + GCB[i,d] )
// Sparsity: AA (64x64, ~50% dense) -> per row-group s, support supp(s).
// Round-7: FRAGMENT-DIRECT gemm (no LDS). r2-r6 showed every global_load_lds
//   variant pins at the LDS-DMA staging path (~8-12 TB/s). Bypass it: prep
//   writes operands PRE-PACKED in MFMA-fragment order:
//     AF[s][ci][h][mg][lane*8]  (1KB = one wave-coalesced dwordx4 load)
//     XF[c][h][g][lane*8]
//   gemm: per (s,np) block, 4 waves, acc[4][4]; K-loop = 16 coalesced global
//   loads + 32 MFMA per support tile, 2-set ping-pong (static reg indexing),
//   no barriers. X XCD-affine (2MB/L2); A streams via LLC. Summation order
//   (ascending c) identical to r4.
// Fallback to fused single-kernel path if ws too small.

#define NC 64
#define NS 64
#define NT 64
#define DH 128
#define BATCH 16
#define MDIM 4096
#define KDIM 4096
#define TM 128
#define TK 64

typedef __attribute__((ext_vector_type(8))) short short8;
typedef __attribute__((ext_vector_type(4))) short short4v;
typedef __attribute__((ext_vector_type(4))) float floatx4;

__device__ __forceinline__ unsigned short f2bf(float f) {
    union { float f; unsigned int i; } v; v.f = f;
    return (unsigned short)((v.i + 0x7fffu + ((v.i >> 16) & 1u)) >> 16);
}

// ---- fused prep ----
// blocks [0,1024): A-fragments. block: s = blk>>4, ci in {blk&15,+16,+32,+48} < ns.
//   AF value at (s,ci,h,mg,lane,e): tt=mg*16+(lane&15); i=tt*64+s;
//   t=h*32+(lane>>4)*8+e; c=scidx[ci]; val=relu(GCW[i][t*64+c]).
//   Writes 1KB-coalesced; GCW 256B lines reused across the block's 4 ci via L1.
//   blk&15==0 publishes cidx[s][rank], nsb[s].
// blocks [1024,2048): X-fragments. block: b=blk>>6... (b,c); LDS transpose of
//   h[b,c,:,:] then XF[(c*2+h2)*128 + b*8+gl][lane*8] = bf16(h[b,c,t,d]),
//   t=h2*32+q*8+e, d=gl*16+l15. Both global sides coalesced.
__global__ __launch_bounds__(256)
void prep(const float* __restrict__ aam, const float* __restrict__ gcw,
          const float* __restrict__ hmat,
          unsigned short* __restrict__ AF, unsigned short* __restrict__ XF,
          unsigned short* __restrict__ cidx, int* __restrict__ nsb)
{
    const int tid = threadIdx.x;
    if ((int)blockIdx.x < 1024) {
        const int blk = blockIdx.x;
        const int s   = blk >> 4;
        __shared__ unsigned short scidx[64];
        __shared__ int sns;
        if (tid < 64) {
            float v = aam[(size_t)s * KDIM + tid];
            unsigned long long m = __ballot(v != 0.f);
            int rank = __popcll(m & ((1ull << tid) - 1ull));
            if (v != 0.f) scidx[rank] = (unsigned short)tid;
            if (tid == 0) sns = (int)__popcll(m);
            if ((blk & 15) == 0) {
                if (v != 0.f) cidx[s * 64 + rank] = (unsigned short)tid;
                if (tid == 0) nsb[s] = (int)__popcll(m);
            }
        }
        __syncthreads();
        const int lane = tid & 63;
        const int l15  = lane & 15;
        const int q    = lane >> 4;
#pragma unroll
        for (int cii = 0; cii < 4; ++cii) {
            const int ci = (blk & 15) + cii * 16;
            if (ci >= sns) continue;
            const int c = (int)scidx[ci];
#pragma unroll
            for (int k2 = 0; k2 < 2; ++k2) {
                const int combo = (tid >> 6) * 2 + k2;   // 0..7
                const int hh = combo >> 2;
                const int mg = combo & 3;
                const int tt = mg * 16 + l15;
                const int i  = tt * 64 + s;
                const float* gr = gcw + (size_t)i * KDIM;
                short8 p;
#pragma unroll
                for (int e = 0; e < 8; ++e) {
                    const int t = hh * 32 + q * 8 + e;
                    float v = gr[t * 64 + c];
                    v = v > 0.f ? v : 0.f;
                    p[e] = (short)f2bf(v);
                }
                *(short8*)(AF + ((((size_t)(s * 64 + ci)) * 2 + hh) * 4 + mg) * 512
                              + lane * 8) = p;
            }
        }
    } else {
        const int blk = blockIdx.x - 1024;
        const int b = blk >> 6;
        const int c = blk & 63;
        __shared__ unsigned short sx[64][140];
        const float* hp = hmat + (((size_t)b * NC + c) * NT) * DH;
#pragma unroll
        for (int u = 0; u < 8; ++u) {
            const int idx = u * 1024 + tid * 4;   // float idx in [64t][128d]
            const int t = idx >> 7;
            const int d = idx & 127;
            floatx4 v = *(const floatx4*)(hp + idx);
            short4v p;
#pragma unroll
            for (int e = 0; e < 4; ++e) p[e] = (short)f2bf(v[e]);
            *(short4v*)&sx[t][d] = p;
        }
        __syncthreads();
        const int lane = tid & 63;
        const int l15  = lane & 15;
        const int q    = lane >> 4;
#pragma unroll
        for (int u2 = 0; u2 < 4; ++u2) {
            const int combo = (tid >> 6) * 4 + u2;   // 0..15
            const int h2 = combo >> 3;
            const int gl = combo & 7;
            short8 p;
#pragma unroll
            for (int e = 0; e < 8; ++e)
                p[e] = (short)sx[h2 * 32 + q * 8 + e][gl * 16 + l15];
            *(short8*)(XF + (((size_t)(c * 2 + h2)) * 128 + b * 8 + gl) * 512
                          + lane * 8) = p;
        }
    }
}

// ---- GEMM: fragment-direct, no LDS. block (s, np); wave w owns C[64 x 64] ----
__global__ __launch_bounds__(256)
void gemm(const unsigned short* __restrict__ AF,
          const unsigned short* __restrict__ XF,
          const unsigned short* __restrict__ cidx,
          const int* __restrict__ nsb,
          const float* __restrict__ gcb,
          float* __restrict__ out)
{
    const int tid = threadIdx.x;
    const int bid = blockIdx.x;
    const int np = bid & 7;        // n-panel -> XCD-affine (XF slice 2MB L2-fits)
    const int s  = bid >> 3;       // row-group 0..63

    const int lane  = tid & 63;
    const int w     = tid >> 6;            // 0..3
    const int gbase = np * 16 + w * 4;     // n-16-group base for this wave
    const int l15   = lane & 15;
    const int q     = lane >> 4;

    const int nt  = nsb[s];
    const int clv = (int)cidx[s * 64 + lane];   // lane t holds c(t), valid t<nt

    floatx4 acc[4][4];
#pragma unroll
    for (int mi = 0; mi < 4; ++mi)
#pragma unroll
        for (int ni = 0; ni < 4; ++ni)
            acc[mi][ni] = (floatx4){0.f, 0.f, 0.f, 0.f};

    short8 a0[4], x0[4], a1[4], x1[4];

    auto loadh = [&](short8 af[4], short8 xf[4], int ci, int c, int hh) {
        const size_t ab = ((((size_t)(s * 64 + ci)) * 2 + hh) * 4) * 512 + lane * 8;
#pragma unroll
        for (int mi = 0; mi < 4; ++mi)
            af[mi] = *(const short8*)(AF + ab + mi * 512);
        const size_t xb = (((size_t)(c * 2 + hh)) * 128 + gbase) * 512 + lane * 8;
#pragma unroll
        for (int ni = 0; ni < 4; ++ni)
            xf[ni] = *(const short8*)(XF + xb + ni * 512);
    };
    auto mfmaset = [&](short8 af[4], short8 xf[4]) {
#pragma unroll
        for (int mi = 0; mi < 4; ++mi)
#pragma unroll
            for (int ni = 0; ni < 4; ++ni)
                acc[mi][ni] = __builtin_amdgcn_mfma_f32_16x16x32_bf16(
                    af[mi], xf[ni], acc[mi][ni], 0, 0, 0);
    };

    if (nt > 0) {
        int ccur = __shfl(clv, 0);
        loadh(a0, x0, 0, ccur, 0);
        const int steps = nt * 2;
        for (int k = 0; k + 1 < steps; k += 2) {
            const int t = k >> 1;
            loadh(a1, x1, t, ccur, 1);      // h=1 of tile t (set1 in flight)
            mfmaset(a0, x0);                // compute h=0 of tile t
            if (k + 2 < steps) {
                const int cn = __shfl(clv, t + 1);
                ccur = cn;
                loadh(a0, x0, t + 1, cn, 0);   // h=0 of tile t+1 (set0 in flight)
            }
            mfmaset(a1, x1);                // compute h=1 of tile t
        }
    }

    // epilogue: rows tt = mi*16+q*4+r -> i = tt*64+s; cols n = (gbase+ni)*16+l15
#pragma unroll
    for (int mi = 0; mi < 4; ++mi) {
        const int tt0 = mi * 16 + q * 4;
#pragma unroll
        for (int ni = 0; ni < 4; ++ni) {
            const int n  = (gbase + ni) * 16 + l15;
            const int bb = n >> 7;
            const int d  = n & 127;
#pragma unroll
            for (int r = 0; r < 4; ++r) {
                const int tt = tt0 + r;
                const int i  = tt * 64 + s;
                float v = acc[mi][ni][r] + gcb[(size_t)i * DH + d];
                v = v > 0.f ? v : 0.f;
                out[(((size_t)bb * NS + s) * NT + tt) * DH + d] = v;
            }
        }
    }
}

// ---- fallback: fused kernel (used only if ws too small) ----
#define APAD 40
#define XPAD 20
__global__ __launch_bounds__(256, 2)
void gcn_fused(const float* __restrict__ hmat, const float* __restrict__ aam,
               const float* __restrict__ gcw, const float* __restrict__ gcb,
               float* __restrict__ out)
{
    __shared__ short sA[TM * APAD];
    __shared__ unsigned int sX[DH * XPAD];
    const int tid = threadIdx.x;
    const int bid = blockIdx.x;
    const int mp  = (bid & 7) * 4 + (bid >> 7);
    const int b   = (bid >> 3) & 15;
    const int i0  = mp * TM;
    const int lane = tid & 63;
    const int wm = ((tid >> 6) >> 1) * 64;
    const int wn = ((tid >> 6) & 1) * 64;
    const int l15 = lane & 15;
    const int q   = lane >> 4;
    floatx4 acc[4][4];
#pragma unroll
    for (int mi = 0; mi < 4; ++mi)
#pragma unroll
        for (int ni = 0; ni < 4; ++ni) acc[mi][ni] = (floatx4){0.f,0.f,0.f,0.f};
    const int ar = tid >> 2, ac = (tid & 3) << 3;
    const int kp = tid >> 4, dg = (tid & 15) << 3;
    const int wkey = (tid & 3) << 2;
    for (int k0 = 0; k0 < KDIM; k0 += 32) {
        const size_t ga0 = (size_t)(i0 + ar) * KDIM + (k0 + ac);
        const size_t ga1 = ga0 + (size_t)64 * KDIM;
        floatx4 aa0a = *(const floatx4*)(aam + ga0), aa0b = *(const floatx4*)(aam + ga0 + 4);
        floatx4 ww0a = *(const floatx4*)(gcw + ga0), ww0b = *(const floatx4*)(gcw + ga0 + 4);
        floatx4 aa1a = *(const floatx4*)(aam + ga1), aa1b = *(const floatx4*)(aam + ga1 + 4);
        floatx4 ww1a = *(const floatx4*)(gcw + ga1), ww1b = *(const floatx4*)(gcw + ga1 + 4);
        const int jj = k0 + 2 * kp, tt = jj >> 6, cc = jj & 63;
        const size_t gx0 = ((size_t)(b * NC + cc) * NT + tt) * DH + dg;
        const size_t gx1 = gx0 + (size_t)NT * DH;
        floatx4 x0a = *(const floatx4*)(hmat + gx0), x0b = *(const floatx4*)(hmat + gx0 + 4);
        floatx4 x1a = *(const floatx4*)(hmat + gx1), x1b = *(const floatx4*)(hmat + gx1 + 4);
        __syncthreads();
        short8 p0, p1;
#pragma unroll
        for (int e = 0; e < 4; ++e) {
            float v0 = aa0a[e]*ww0a[e]; v0 = v0>0.f?v0:0.f;
            float v1 = aa0b[e]*ww0b[e]; v1 = v1>0.f?v1:0.f;
            float v2 = aa1a[e]*ww1a[e]; v2 = v2>0.f?v2:0.f;
            float v3 = aa1b[e]*ww1b[e]; v3 = v3>0.f?v3:0.f;
            p0[e] = (short)f2bf(v0); p0[e+4] = (short)f2bf(v1);
            p1[e] = (short)f2bf(v2); p1[e+4] = (short)f2bf(v3);
        }
        *(short8*)&sA[ar * APAD + ac] = p0;
        *(short8*)&sA[(ar + 64) * APAD + ac] = p1;
#pragma unroll
        for (int e = 0; e < 4; ++e) {
            unsigned int pka = (unsigned int)f2bf(x0a[e]) | ((unsigned int)f2bf(x1a[e]) << 16);
            unsigned int pkb = (unsigned int)f2bf(x0b[e]) | ((unsigned int)f2bf(x1b[e]) << 16);
            sX[(dg + e) * XPAD + (kp ^ wkey)] = pka;
            sX[(dg + e + 4) * XPAD + (kp ^ wkey)] = pkb;
        }
        __syncthreads();
        short8 afrag[4], bfrag[4];
#pragma unroll
        for (int mi = 0; mi < 4; ++mi)
            afrag[mi] = *(const short8*)&sA[(wm + mi * 16 + l15) * APAD + q * 8];
#pragma unroll
        for (int ni = 0; ni < 4; ++ni) {
            const int row = wn + ni * 16 + l15;
            const int col = (q * 4) ^ (((row >> 3) & 3) << 2);
            bfrag[ni] = *(const short8*)(sX + row * XPAD + col);
        }
#pragma unroll
        for (int mi = 0; mi < 4; ++mi)
#pragma unroll
            for (int ni = 0; ni < 4; ++ni)
                acc[mi][ni] = __builtin_amdgcn_mfma_f32_16x16x32_bf16(
                    afrag[mi], bfrag[ni], acc[mi][ni], 0, 0, 0);
    }
#pragma unroll
    for (int mi = 0; mi < 4; ++mi) {
        const int ibase = i0 + wm + mi * 16 + q * 4;
#pragma unroll
        for (int ni = 0; ni < 4; ++ni) {
            const int d = wn + ni * 16 + l15;
#pragma unroll
            for (int r = 0; r < 4; ++r) {
                const int i = ibase + r;
                float v = acc[mi][ni][r] + gcb[(size_t)i * DH + d];
                v = v > 0.f ? v : 0.f;
                out[(((size_t)b * NS + (i & 63)) * NT + (i >> 6)) * DH + d] = v;
            }
        }
    }
}

extern "C" void kernel_launch(void* const* d_in, const int* in_sizes, int n_in,
                              void* d_out, int out_size, void* d_ws, size_t ws_size,
                              hipStream_t stream) {
    const float* h   = (const float*)d_in[0];
    const float* aam = (const float*)d_in[2];
    const float* gcw = (const float*)d_in[3];
    const float* gcb = (const float*)d_in[4];
    float* out = (float*)d_out;

    const size_t A_BYTES   = (size_t)64 * 64 * 8 * 512 * 2;      // AF: 33.55 MB
    const size_t X_BYTES   = (size_t)64 * 2 * 128 * 512 * 2;     // XF: 16.78 MB
    const size_t IDX_BYTES = 64 * 64 * 2;                        // 8 KB
    const size_t NS_BYTES  = 64 * 4;

    if (ws_size >= A_BYTES + X_BYTES + IDX_BYTES + NS_BYTES) {
        unsigned short* AF = (unsigned short*)d_ws;
        unsigned short* XF = (unsigned short*)((char*)d_ws + A_BYTES);
        unsigned short* ci = (unsigned short*)((char*)d_ws + A_BYTES + X_BYTES);
        int* nsb           = (int*)((char*)d_ws + A_BYTES + X_BYTES + IDX_BYTES);
        prep<<<dim3(2048), 256, 0, stream>>>(aam, gcw, h, AF, XF, ci, nsb);
        gemm<<<dim3(64 * 8), 256, 0, stream>>>(AF, XF, ci, nsb, gcb, out);
    } else {
        gcn_fused<<<dim3((MDIM / TM) * BATCH), 256, 0, stream>>>(h, aam, gcw, gcb, out);
    }
}

// Round 8
// 258.544 us; speedup vs baseline: 1.4373x; 1.4373x over previous
//
#include <hip/hip_runtime.h>

// GCNFast: out[b,s,t,d] = relu( sum_j relu(AA[i%64,j%64]*GCW[i,j]) * X[j,b,d] + GCB[i,d] )
// Sparsity: AA (64x64, ~50% dense) -> per row-group s, support supp(s).
// Round-8: HYBRID gemm. r2-r6: one LDS-DMA pipe @ ~10.5 TB/s bound all staged
//   variants; X re-staging was 80% of its traffic. r7: all-direct was latency-
//   bound, and its A-fragment prep overfetched 7x. Hybrid: A' stays on the
//   proven LDS dbuf/counted-vmcnt pipe (8KB/tile, 3 bufs, vmcnt 18/16/0);
//   X read fragment-direct from XCD-L2 (XF layout, r7-proven addressing),
//   2-deep named-set register ping-pong. prep: r5 per-row A-gather (proven,
//   no overfetch) + r7 X-fragment builder. Summation order (ascending c)
//   identical to r4/r5 -> same numerics.
// Fallback to fused single-kernel path if ws too small.

#define NC 64
#define NS 64
#define NT 64
#define DH 128
#define BATCH 16
#define MDIM 4096
#define KDIM 4096
#define KPAD 4096
#define TM 128
#define TK 64
#define GBM 64
#define GBK 64

typedef __attribute__((ext_vector_type(8))) short short8;
typedef __attribute__((ext_vector_type(4))) short short4v;
typedef __attribute__((ext_vector_type(4))) float floatx4;

__device__ __forceinline__ unsigned short f2bf(float f) {
    union { float f; unsigned int i; } v; v.f = f;
    return (unsigned short)((v.i + 0x7fffu + ((v.i >> 16) & 1u)) >> 16);
}
__device__ __forceinline__ void async16(const void* g, void* l) {
    __builtin_amdgcn_global_load_lds(
        (const __attribute__((address_space(1))) void*)g,
        (__attribute__((address_space(3))) void*)l, 16, 0, 0);
}

// ---- fused prep ----
// blocks [0,4096): A' row r=s*64+tt (orig row i=tt*64+s):
//   A'[r][ci*64+t] = relu(GCW[i][t*64+cidx[s][ci]]) via per-row direct gather
//   (row 16KB fits L1; 8 scattered reads/thread are L1 hits), coalesced 16B
//   writes. tt==0 publishes cidx[s][.], nsb[s].
// blocks [4096,5120): X-fragments XF[(c*2+h2)*128 + b*8+gl][lane*8+e] =
//   bf16(h[b, c, t=h2*32+q*8+e, d=gl*16+l15]) via LDS transpose; both global
//   sides coalesced. (r7-proven.)
__global__ __launch_bounds__(256)
void prep(const float* __restrict__ aam, const float* __restrict__ gcw,
          const float* __restrict__ hmat,
          unsigned short* __restrict__ Abf, unsigned short* __restrict__ XF,
          unsigned short* __restrict__ cidx, int* __restrict__ nsb)
{
    const int tid = threadIdx.x;
    if ((int)blockIdx.x < MDIM) {
        const int r  = blockIdx.x;
        const int s  = r >> 6;
        const int tt = r & 63;
        const int i  = tt * 64 + s;
        __shared__ unsigned short scidx[64];
        __shared__ int sns;
        if (tid < 64) {
            float v = aam[(size_t)s * KDIM + tid];
            unsigned long long m = __ballot(v != 0.f);
            int rank = __popcll(m & ((1ull << tid) - 1ull));
            if (v != 0.f) scidx[rank] = (unsigned short)tid;
            if (tid == 0) sns = (int)__popcll(m);
            if (tt == 0) {
                if (v != 0.f) cidx[s * 64 + rank] = (unsigned short)tid;
                if (tid == 0) nsb[s] = (int)__popcll(m);
            }
        }
        __syncthreads();
        const int ke = sns * 64;   // multiple of 64
        const float* gr = gcw + (size_t)i * KDIM;
        for (int kk0 = tid * 8; kk0 < ke; kk0 += 2048) {
            const int c  = (int)scidx[kk0 >> 6];
            const int t0 = kk0 & 63;   // multiple of 8
            short8 p;
#pragma unroll
            for (int e = 0; e < 8; ++e) {
                float v = gr[(t0 + e) * 64 + c];
                v = v > 0.f ? v : 0.f;
                p[e] = (short)f2bf(v);
            }
            *(short8*)(Abf + (size_t)r * KPAD + kk0) = p;
        }
    } else {
        const int blk = blockIdx.x - MDIM;
        const int b = blk >> 6;
        const int c = blk & 63;
        __shared__ unsigned short sx[64][140];
        const float* hp = hmat + (((size_t)b * NC + c) * NT) * DH;
#pragma unroll
        for (int u = 0; u < 8; ++u) {
            const int idx = u * 1024 + tid * 4;   // float idx in [64t][128d]
            const int t = idx >> 7;
            const int d = idx & 127;
            floatx4 v = *(const floatx4*)(hp + idx);
            short4v p;
#pragma unroll
            for (int e = 0; e < 4; ++e) p[e] = (short)f2bf(v[e]);
            *(short4v*)&sx[t][d] = p;
        }
        __syncthreads();
        const int lane = tid & 63;
        const int l15  = lane & 15;
        const int q    = lane >> 4;
#pragma unroll
        for (int u2 = 0; u2 < 4; ++u2) {
            const int combo = (tid >> 6) * 4 + u2;   // 0..15
            const int h2 = combo >> 3;
            const int gl = combo & 7;
            short8 p;
#pragma unroll
            for (int e = 0; e < 8; ++e)
                p[e] = (short)sx[h2 * 32 + q * 8 + e][gl * 16 + l15];
            *(short8*)(XF + (((size_t)(c * 2 + h2)) * 128 + b * 8 + gl) * 512
                          + lane * 8) = p;
        }
    }
}

// ---- GEMM: per-(s,np) block, 4 waves, C[64 x 256/..]; A via LDS, X direct ----
__global__ __launch_bounds__(256)
void gemm(const unsigned short* __restrict__ Abf,
          const unsigned short* __restrict__ XF,
          const unsigned short* __restrict__ cidx,
          const int* __restrict__ nsb,
          const float* __restrict__ gcb,
          float* __restrict__ out)
{
    __shared__ short ldsA[3][GBM * GBK];   // 3 x 8 KB

    const int tid = threadIdx.x;
    const int bid = blockIdx.x;
    const int np = bid & 7;        // n-panel -> XCD-affine (XF slice 2MB L2-fits)
    const int s  = bid >> 3;       // row-group 0..63

    const int lane  = tid & 63;
    const int w     = tid >> 6;            // 0..3
    const int gbase = np * 16 + w * 4;     // n-16-group base for this wave
    const int l15   = lane & 15;
    const int q     = lane >> 4;
    const int srow  = lane >> 3;
    const int swz   = ((lane & 7) ^ srow) << 3;   // swizzled k-chunk (elements)

    const int nt  = nsb[s];
    const int clv = (int)cidx[s * 64 + lane];   // lane t holds c(t), valid t<nt

    const unsigned short* Ab = Abf + (size_t)(s * 64) * KPAD + swz;

    floatx4 acc[4][4];
#pragma unroll
    for (int mi = 0; mi < 4; ++mi)
#pragma unroll
        for (int ni = 0; ni < 4; ++ni)
            acc[mi][ni] = (floatx4){0.f, 0.f, 0.f, 0.f};

    short8 xa0[4], xa1[4], xb0[4], xb1[4];   // 2 named sets (static indexing)

    auto stagea = [&](int t) {               // 2 async16/wave -> ldsA[t%3]
        short* dst = ldsA[t % 3];
        const size_t ka = (size_t)t * GBK;   // A' compact: tile index == ci
        async16(Ab + (size_t)(w * 8 + srow) * KPAD + ka,       dst + (w * 8) * GBK);
        async16(Ab + (size_t)((w + 4) * 8 + srow) * KPAD + ka, dst + ((w + 4) * 8) * GBK);
    };
    auto loadx = [&](short8 (&h0)[4], short8 (&h1)[4], int t) {  // 16 x 1KB coalesced
        const int c = __shfl(clv, t);
        size_t xb = ((size_t)(c * 2) * 128 + gbase) * 512 + lane * 8;
#pragma unroll
        for (int ni = 0; ni < 4; ++ni) h0[ni] = *(const short8*)(XF + xb + ni * 512);
        xb += (size_t)128 * 512;
#pragma unroll
        for (int ni = 0; ni < 4; ++ni) h1[ni] = *(const short8*)(XF + xb + ni * 512);
    };
    auto compute = [&](int t, short8 (&h0)[4], short8 (&h1)[4]) {
        const short* sA = ldsA[t % 3];
#pragma unroll
        for (int h2 = 0; h2 < 2; ++h2) {
            const int co = ((h2 * 4 + q) ^ (l15 & 7)) << 3;
            short8 af[4];
#pragma unroll
            for (int mi = 0; mi < 4; ++mi)
                af[mi] = *(const short8*)&sA[(mi * 16 + l15) * GBK + co];
            __builtin_amdgcn_s_setprio(1);
#pragma unroll
            for (int mi = 0; mi < 4; ++mi)
#pragma unroll
                for (int ni = 0; ni < 4; ++ni)
                    acc[mi][ni] = __builtin_amdgcn_mfma_f32_16x16x32_bf16(
                        af[mi], h2 ? h1[ni] : h0[ni], acc[mi][ni], 0, 0, 0);
            __builtin_amdgcn_s_setprio(0);
        }
    };

    if (nt > 0) stagea(0);
    if (nt > 1) stagea(1);
    if (nt > 0) loadx(xa0, xa1, 0);

    int t = 0, cur = 0;
    while (t < nt) {
        __builtin_amdgcn_s_barrier();        // all waves done reading ldsA[(t+2)%3]
        if (t + 2 < nt) stagea(t + 2);
        if (t + 1 < nt) {
            if (cur == 0) loadx(xb0, xb1, t + 1);
            else          loadx(xa0, xa1, t + 1);
        }
        // steady: keep newest 18 (2 A-DMA + 16 X) in flight; retires X(t), A(t)
        if (t + 2 < nt)      asm volatile("s_waitcnt vmcnt(18)" ::: "memory");
        else if (t + 1 < nt) asm volatile("s_waitcnt vmcnt(16)" ::: "memory");
        else                 asm volatile("s_waitcnt vmcnt(0)"  ::: "memory");
        __builtin_amdgcn_s_barrier();        // A(t) visible to all waves
        if (cur == 0) compute(t, xa0, xa1);
        else          compute(t, xb0, xb1);
        cur ^= 1;
        ++t;
    }

    // epilogue: rows tt = mi*16+q*4+r -> i = tt*64+s; cols n = (gbase+ni)*16+l15
#pragma unroll
    for (int mi = 0; mi < 4; ++mi) {
        const int tt0 = mi * 16 + q * 4;
#pragma unroll
        for (int ni = 0; ni < 4; ++ni) {
            const int n  = (gbase + ni) * 16 + l15;
            const int bb = n >> 7;
            const int d  = n & 127;
#pragma unroll
            for (int r2 = 0; r2 < 4; ++r2) {
                const int tt = tt0 + r2;
                const int i  = tt * 64 + s;
                float v = acc[mi][ni][r2] + gcb[(size_t)i * DH + d];
                v = v > 0.f ? v : 0.f;
                out[(((size_t)bb * NS + s) * NT + tt) * DH + d] = v;
            }
        }
    }
}

// ---- fallback: fused kernel (used only if ws too small) ----
#define APAD 40
#define XPAD 20
__global__ __launch_bounds__(256, 2)
void gcn_fused(const float* __restrict__ hmat, const float* __restrict__ aam,
               const float* __restrict__ gcw, const float* __restrict__ gcb,
               float* __restrict__ out)
{
    __shared__ short sA[TM * APAD];
    __shared__ unsigned int sX[DH * XPAD];
    const int tid = threadIdx.x;
    const int bid = blockIdx.x;
    const int mp  = (bid & 7) * 4 + (bid >> 7);
    const int b   = (bid >> 3) & 15;
    const int i0  = mp * TM;
    const int lane = tid & 63;
    const int wm = ((tid >> 6) >> 1) * 64;
    const int wn = ((tid >> 6) & 1) * 64;
    const int l15 = lane & 15;
    const int q   = lane >> 4;
    floatx4 acc[4][4];
#pragma unroll
    for (int mi = 0; mi < 4; ++mi)
#pragma unroll
        for (int ni = 0; ni < 4; ++ni) acc[mi][ni] = (floatx4){0.f,0.f,0.f,0.f};
    const int ar = tid >> 2, ac = (tid & 3) << 3;
    const int kp = tid >> 4, dg = (tid & 15) << 3;
    const int wkey = (tid & 3) << 2;
    for (int k0 = 0; k0 < KDIM; k0 += 32) {
        const size_t ga0 = (size_t)(i0 + ar) * KDIM + (k0 + ac);
        const size_t ga1 = ga0 + (size_t)64 * KDIM;
        floatx4 aa0a = *(const floatx4*)(aam + ga0), aa0b = *(const floatx4*)(aam + ga0 + 4);
        floatx4 ww0a = *(const floatx4*)(gcw + ga0), ww0b = *(const floatx4*)(gcw + ga0 + 4);
        floatx4 aa1a = *(const floatx4*)(aam + ga1), aa1b = *(const floatx4*)(aam + ga1 + 4);
        floatx4 ww1a = *(const floatx4*)(gcw + ga1), ww1b = *(const floatx4*)(gcw + ga1 + 4);
        const int jj = k0 + 2 * kp, tt = jj >> 6, cc = jj & 63;
        const size_t gx0 = ((size_t)(b * NC + cc) * NT + tt) * DH + dg;
        const size_t gx1 = gx0 + (size_t)NT * DH;
        floatx4 x0a = *(const floatx4*)(hmat + gx0), x0b = *(const floatx4*)(hmat + gx0 + 4);
        floatx4 x1a = *(const floatx4*)(hmat + gx1), x1b = *(const floatx4*)(hmat + gx1 + 4);
        __syncthreads();
        short8 p0, p1;
#pragma unroll
        for (int e = 0; e < 4; ++e) {
            float v0 = aa0a[e]*ww0a[e]; v0 = v0>0.f?v0:0.f;
            float v1 = aa0b[e]*ww0b[e]; v1 = v1>0.f?v1:0.f;
            float v2 = aa1a[e]*ww1a[e]; v2 = v2>0.f?v2:0.f;
            float v3 = aa1b[e]*ww1b[e]; v3 = v3>0.f?v3:0.f;
            p0[e] = (short)f2bf(v0); p0[e+4] = (short)f2bf(v1);
            p1[e] = (short)f2bf(v2); p1[e+4] = (short)f2bf(v3);
        }
        *(short8*)&sA[ar * APAD + ac] = p0;
        *(short8*)&sA[(ar + 64) * APAD + ac] = p1;
#pragma unroll
        for (int e = 0; e < 4; ++e) {
            unsigned int pka = (unsigned int)f2bf(x0a[e]) | ((unsigned int)f2bf(x1a[e]) << 16);
            unsigned int pkb = (unsigned int)f2bf(x0b[e]) | ((unsigned int)f2bf(x1b[e]) << 16);
            sX[(dg + e) * XPAD + (kp ^ wkey)] = pka;
            sX[(dg + e + 4) * XPAD + (kp ^ wkey)] = pkb;
        }
        __syncthreads();
        short8 afrag[4], bfrag[4];
#pragma unroll
        for (int mi = 0; mi < 4; ++mi)
            afrag[mi] = *(const short8*)&sA[(wm + mi * 16 + l15) * APAD + q * 8];
#pragma unroll
        for (int ni = 0; ni < 4; ++ni) {
            const int row = wn + ni * 16 + l15;
            const int col = (q * 4) ^ (((row >> 3) & 3) << 2);
            bfrag[ni] = *(const short8*)(sX + row * XPAD + col);
        }
#pragma unroll
        for (int mi = 0; mi < 4; ++mi)
#pragma unroll
            for (int ni = 0; ni < 4; ++ni)
                acc[mi][ni] = __builtin_amdgcn_mfma_f32_16x16x32_bf16(
                    afrag[mi], bfrag[ni], acc[mi][ni], 0, 0, 0);
    }
#pragma unroll
    for (int mi = 0; mi < 4; ++mi) {
        const int ibase = i0 + wm + mi * 16 + q * 4;
#pragma unroll
        for (int ni = 0; ni < 4; ++ni) {
            const int d = wn + ni * 16 + l15;
#pragma unroll
            for (int r = 0; r < 4; ++r) {
                const int i = ibase + r;
                float v = acc[mi][ni][r] + gcb[(size_t)i * DH + d];
                v = v > 0.f ? v : 0.f;
                out[(((size_t)b * NS + (i & 63)) * NT + (i >> 6)) * DH + d] = v;
            }
        }
    }
}

extern "C" void kernel_launch(void* const* d_in, const int* in_sizes, int n_in,
                              void* d_out, int out_size, void* d_ws, size_t ws_size,
                              hipStream_t stream) {
    const float* h   = (const float*)d_in[0];
    const float* aam = (const float*)d_in[2];
    const float* gcw = (const float*)d_in[3];
    const float* gcb = (const float*)d_in[4];
    float* out = (float*)d_out;

    const size_t A_BYTES   = (size_t)MDIM * KPAD * 2;            // A': 33.55 MB
    const size_t X_BYTES   = (size_t)64 * 2 * 128 * 512 * 2;     // XF: 16.78 MB
    const size_t IDX_BYTES = 64 * 64 * 2;                        // 8 KB
    const size_t NS_BYTES  = 64 * 4;

    if (ws_size >= A_BYTES + X_BYTES + IDX_BYTES + NS_BYTES) {
        unsigned short* Abf = (unsigned short*)d_ws;
        unsigned short* XF  = (unsigned short*)((char*)d_ws + A_BYTES);
        unsigned short* cid = (unsigned short*)((char*)d_ws + A_BYTES + X_BYTES);
        int* nsb            = (int*)((char*)d_ws + A_BYTES + X_BYTES + IDX_BYTES);
        prep<<<dim3(MDIM + 1024), 256, 0, stream>>>(aam, gcw, h, Abf, XF, cid, nsb);
        gemm<<<dim3(64 * 8), 256, 0, stream>>>(Abf, XF, cid, nsb, gcb, out);
    } else {
        gcn_fused<<<dim3((MDIM / TM) * BATCH), 256, 0, stream>>>(h, aam, gcw, gcb, out);
    }
}

// Round 9
// 254.540 us; speedup vs baseline: 1.4600x; 1.0157x over previous
//
#include <hip/hip_runtime.h>

// GCNFast: out[b,s,t,d] = relu( sum_j relu(AA[i%64,j%64]*GCW[i,j]) * X[j,b,d] + GCB[i,d] )
// Sparsity: AA (64x64, ~50% dense) -> per row-group s, support supp(s) in c.
// K reordered kk=c*64+t; A' compact [s*64+tt][ci*64+t], XT' [b*128+d][c*64+t].
// Round-9: REVERT to r4 (best: gemm 63us, total 229) + ONE change: staging
//   pipeline depth 1 -> 2 (3 LDS buffers, vmcnt 20/10/0). r4 ran 1 block/CU
//   anyway (80KB exact-fit failed) and was fastest => occupancy irrelevant,
//   pipe depth is the only free variable. 120KB LDS, same proven stage/compute
//   lambdas and barrier placement. prep = r5 verbatim (per-row A gather +
//   LDS-transpose X). Summation order (ascending c) identical to r4.
// Fallback to fused single-kernel path if ws too small.

#define NC 64
#define NS 64
#define NT 64
#define DH 128
#define BATCH 16
#define MDIM 4096
#define KDIM 4096
#define KPAD 4096
#define TM 128
#define TK 64
#define GBM 64
#define GBN 256
#define GBK 64

typedef __attribute__((ext_vector_type(8))) short short8;
typedef __attribute__((ext_vector_type(4))) short short4v;
typedef __attribute__((ext_vector_type(4))) float floatx4;

__device__ __forceinline__ unsigned short f2bf(float f) {
    union { float f; unsigned int i; } v; v.f = f;
    return (unsigned short)((v.i + 0x7fffu + ((v.i >> 16) & 1u)) >> 16);
}
__device__ __forceinline__ void async16(const void* g, void* l) {
    __builtin_amdgcn_global_load_lds(
        (const __attribute__((address_space(1))) void*)g,
        (__attribute__((address_space(3))) void*)l, 16, 0, 0);
}

// ---- fused prep (r5 verbatim) ----
// blocks [0,4096): A'[r=s*64+tt][ci*64+t] = relu(GCW[tt*64+s][t*64+cidx[s][ci]])
//   via direct global gather (row 16KB L1-resident) -> coalesced short8 writes.
//   tt==0 publishes cidx[s][.], ns[s].
// blocks [4096,5120): XT'[b*128+d][c*64+t] = bf16(h[b,c,t,d]) via LDS transpose.
__global__ __launch_bounds__(256)
void prep(const float* __restrict__ aam, const float* __restrict__ gcw,
          const float* __restrict__ hmat,
          unsigned short* __restrict__ Abf, unsigned short* __restrict__ XT,
          unsigned short* __restrict__ cidx, int* __restrict__ nsb)
{
    const int tid = threadIdx.x;
    if ((int)blockIdx.x < MDIM) {
        const int r  = blockIdx.x;
        const int s  = r >> 6;
        const int tt = r & 63;
        const int i  = tt * 64 + s;
        __shared__ unsigned short scidx[64];
        __shared__ int sns;
        if (tid < 64) {
            float v = aam[(size_t)s * KDIM + tid];
            unsigned long long m = __ballot(v != 0.f);
            int rank = __popcll(m & ((1ull << tid) - 1ull));
            if (v != 0.f) scidx[rank] = (unsigned short)tid;
            if (tid == 0) sns = (int)__popcll(m);
            if (tt == 0) {
                if (v != 0.f) cidx[s * 64 + rank] = (unsigned short)tid;
                if (tid == 0) nsb[s] = (int)__popcll(m);
            }
        }
        __syncthreads();
        const int ke = sns * 64;   // multiple of 64
        const float* gr = gcw + (size_t)i * KDIM;
        for (int kk0 = tid * 8; kk0 < ke; kk0 += 2048) {
            const int c  = (int)scidx[kk0 >> 6];
            const int t0 = kk0 & 63;   // multiple of 8
            short8 p;
#pragma unroll
            for (int e = 0; e < 8; ++e) {
                float v = gr[(t0 + e) * 64 + c];
                v = v > 0.f ? v : 0.f;
                p[e] = (short)f2bf(v);
            }
            *(short8*)(Abf + (size_t)r * KPAD + kk0) = p;
        }
    } else {
        const int blk = blockIdx.x - MDIM;
        const int b = blk >> 6;
        const int c = blk & 63;
        __shared__ unsigned short sx[64][136];
        const float* hp = hmat + (((size_t)b * NC + c) * NT) * DH;
#pragma unroll
        for (int u = 0; u < 8; ++u) {
            const int idx = u * 1024 + tid * 4;   // float idx in [64t][128d]
            const int t = idx >> 7;
            const int d = idx & 127;
            floatx4 v = *(const floatx4*)(hp + idx);
            short4v p;
#pragma unroll
            for (int e = 0; e < 4; ++e) p[e] = (short)f2bf(v[e]);
            *(short4v*)&sx[t][d] = p;
        }
        __syncthreads();
        const int d  = tid >> 1;
        const int th = (tid & 1) * 32;
        unsigned short* dst = XT + ((size_t)(b * DH + d)) * KPAD + c * 64 + th;
#pragma unroll
        for (int u2 = 0; u2 < 4; ++u2) {
            short8 p;
#pragma unroll
            for (int e = 0; e < 8; ++e)
                p[e] = (short)sx[th + u2 * 8 + e][d];
            *(short8*)(dst + u2 * 8) = p;
        }
    }
}

// ---- GEMM: per-s tile C[64, 256], K over ns[s] nonzero c-tiles, 3-buf depth-2 ----
__global__ __launch_bounds__(256, 2)
void gemm(const unsigned short* __restrict__ Abf,
          const unsigned short* __restrict__ XT,
          const unsigned short* __restrict__ cidx,
          const int* __restrict__ nsb,
          const float* __restrict__ gcb,
          float* __restrict__ out)
{
    __shared__ short lds[3][(GBM + GBN) * GBK];   // 3 x 40 KB = 120 KB (1 block/CU)

    const int tid = threadIdx.x;
    const int bid = blockIdx.x;
    const int np = bid & 7;        // n-panel -> one per XCD (XT' panel 2MB L2-fits)
    const int s  = bid >> 3;       // row-group 0..63
    const int n0 = np * GBN;

    const int lane = tid & 63;
    const int w    = tid >> 6;     // 0..3
    const int wn   = w * 64;
    const int l15  = lane & 15;
    const int q    = lane >> 4;
    const int srow = lane >> 3;
    const int swz  = ((lane & 7) ^ srow) << 3;   // swizzled k-chunk (elements)

    const int nt = nsb[s];                        // K-tiles = |supp(s)|
    const int cl = (int)cidx[s * 64 + lane];      // lane t holds c(t) (t<nt valid)

    const unsigned short* Ab = Abf + (size_t)(s * 64) * KPAD + swz;
    const unsigned short* Xb = XT  + (size_t)n0 * KPAD + swz;

    floatx4 acc[4][4];
#pragma unroll
    for (int mi = 0; mi < 4; ++mi)
#pragma unroll
        for (int ni = 0; ni < 4; ++ni)
            acc[mi][ni] = (floatx4){0.f, 0.f, 0.f, 0.f};

    // 10 global_load_lds per wave per tile (2 A-groups + 8 X-groups)
    auto stage = [&](int t, int b) {
        short* dst = lds[b];
        const int c = __shfl(cl, t);
        const size_t ka = (size_t)t * GBK;   // A' compact k-offset
        const size_t kx = (size_t)c * GBK;   // XT' reordered k-offset
        async16(Ab + (size_t)(w * 8 + srow) * KPAD + ka,       dst + (w * 8) * GBK);
        async16(Ab + (size_t)((w + 4) * 8 + srow) * KPAD + ka, dst + ((w + 4) * 8) * GBK);
#pragma unroll
        for (int g = 0; g < 8; ++g) {
            const int rr = w * 64 + g * 8;
            async16(Xb + (size_t)(rr + srow) * KPAD + kx, dst + (GBM + rr) * GBK);
        }
    };

    auto compute = [&](int b) {
        const short* sA = lds[b];
        const short* sX = lds[b] + GBM * GBK;
#pragma unroll
        for (int h2 = 0; h2 < 2; ++h2) {
            const int co = ((h2 * 4 + q) ^ (l15 & 7)) << 3;
            short8 af[4], xf[4];
#pragma unroll
            for (int mi = 0; mi < 4; ++mi)
                af[mi] = *(const short8*)&sA[(mi * 16 + l15) * GBK + co];
#pragma unroll
            for (int ni = 0; ni < 4; ++ni)
                xf[ni] = *(const short8*)&sX[(wn + ni * 16 + l15) * GBK + co];
            __builtin_amdgcn_s_setprio(1);
#pragma unroll
            for (int mi = 0; mi < 4; ++mi)
#pragma unroll
                for (int ni = 0; ni < 4; ++ni)
                    acc[mi][ni] = __builtin_amdgcn_mfma_f32_16x16x32_bf16(
                        af[mi], xf[ni], acc[mi][ni], 0, 0, 0);
            __builtin_amdgcn_s_setprio(0);
        }
    };

    if (nt > 0) stage(0, 0);
    if (nt > 1) stage(1, 1);
    if (nt > 2) stage(2, 2);
    for (int t = 0; t < nt; ++t) {
        // in-flight tiles beyond t: min(nt-1-t, 2); wait until tile t's 10 landed
        const int rem = nt - 1 - t;
        if (rem >= 2)      asm volatile("s_waitcnt vmcnt(20)" ::: "memory");
        else if (rem == 1) asm volatile("s_waitcnt vmcnt(10)" ::: "memory");
        else               asm volatile("s_waitcnt vmcnt(0)"  ::: "memory");
        __builtin_amdgcn_s_barrier();
        const int b = t % 3;
        compute(b);
        __builtin_amdgcn_s_barrier();        // all waves done reading lds[b]
        if (t + 3 < nt) stage(t + 3, b);     // overwrite just-consumed buffer
    }

    // epilogue: row-in-tile tt -> original i = tt*64 + s; out[b, s, tt, d]
#pragma unroll
    for (int mi = 0; mi < 4; ++mi) {
        const int tt0 = mi * 16 + q * 4;
#pragma unroll
        for (int ni = 0; ni < 4; ++ni) {
            const int n  = n0 + wn + ni * 16 + l15;
            const int bb = n >> 7;
            const int d  = n & 127;
#pragma unroll
            for (int r = 0; r < 4; ++r) {
                const int tt = tt0 + r;
                const int i  = tt * 64 + s;
                float v = acc[mi][ni][r] + gcb[(size_t)i * DH + d];
                v = v > 0.f ? v : 0.f;
                out[(((size_t)bb * NS + s) * NT + tt) * DH + d] = v;
            }
        }
    }
}

// ---- fallback: fused kernel (used only if ws too small) ----
#define APAD 40
#define XPAD 20
__global__ __launch_bounds__(256, 2)
void gcn_fused(const float* __restrict__ hmat, const float* __restrict__ aam,
               const float* __restrict__ gcw, const float* __restrict__ gcb,
               float* __restrict__ out)
{
    __shared__ short sA[TM * APAD];
    __shared__ unsigned int sX[DH * XPAD];
    const int tid = threadIdx.x;
    const int bid = blockIdx.x;
    const int mp  = (bid & 7) * 4 + (bid >> 7);
    const int b   = (bid >> 3) & 15;
    const int i0  = mp * TM;
    const int lane = tid & 63;
    const int wm = ((tid >> 6) >> 1) * 64;
    const int wn = ((tid >> 6) & 1) * 64;
    const int l15 = lane & 15;
    const int q   = lane >> 4;
    floatx4 acc[4][4];
#pragma unroll
    for (int mi = 0; mi < 4; ++mi)
#pragma unroll
        for (int ni = 0; ni < 4; ++ni) acc[mi][ni] = (floatx4){0.f,0.f,0.f,0.f};
    const int ar = tid >> 2, ac = (tid & 3) << 3;
    const int kp = tid >> 4, dg = (tid & 15) << 3;
    const int wkey = (tid & 3) << 2;
    for (int k0 = 0; k0 < KDIM; k0 += 32) {
        const size_t ga0 = (size_t)(i0 + ar) * KDIM + (k0 + ac);
        const size_t ga1 = ga0 + (size_t)64 * KDIM;
        floatx4 aa0a = *(const floatx4*)(aam + ga0), aa0b = *(const floatx4*)(aam + ga0 + 4);
        floatx4 ww0a = *(const floatx4*)(gcw + ga0), ww0b = *(const floatx4*)(gcw + ga0 + 4);
        floatx4 aa1a = *(const floatx4*)(aam + ga1), aa1b = *(const floatx4*)(aam + ga1 + 4);
        floatx4 ww1a = *(const floatx4*)(gcw + ga1), ww1b = *(const floatx4*)(gcw + ga1 + 4);
        const int jj = k0 + 2 * kp, tt = jj >> 6, cc = jj & 63;
        const size_t gx0 = ((size_t)(b * NC + cc) * NT + tt) * DH + dg;
        const size_t gx1 = gx0 + (size_t)NT * DH;
        floatx4 x0a = *(const floatx4*)(hmat + gx0), x0b = *(const floatx4*)(hmat + gx0 + 4);
        floatx4 x1a = *(const floatx4*)(hmat + gx1), x1b = *(const floatx4*)(hmat + gx1 + 4);
        __syncthreads();
        short8 p0, p1;
#pragma unroll
        for (int e = 0; e < 4; ++e) {
            float v0 = aa0a[e]*ww0a[e]; v0 = v0>0.f?v0:0.f;
            float v1 = aa0b[e]*ww0b[e]; v1 = v1>0.f?v1:0.f;
            float v2 = aa1a[e]*ww1a[e]; v2 = v2>0.f?v2:0.f;
            float v3 = aa1b[e]*ww1b[e]; v3 = v3>0.f?v3:0.f;
            p0[e] = (short)f2bf(v0); p0[e+4] = (short)f2bf(v1);
            p1[e] = (short)f2bf(v2); p1[e+4] = (short)f2bf(v3);
        }
        *(short8*)&sA[ar * APAD + ac] = p0;
        *(short8*)&sA[(ar + 64) * APAD + ac] = p1;
#pragma unroll
        for (int e = 0; e < 4; ++e) {
            unsigned int pka = (unsigned int)f2bf(x0a[e]) | ((unsigned int)f2bf(x1a[e]) << 16);
            unsigned int pkb = (unsigned int)f2bf(x0b[e]) | ((unsigned int)f2bf(x1b[e]) << 16);
            sX[(dg + e) * XPAD + (kp ^ wkey)] = pka;
            sX[(dg + e + 4) * XPAD + (kp ^ wkey)] = pkb;
        }
        __syncthreads();
        short8 afrag[4], bfrag[4];
#pragma unroll
        for (int mi = 0; mi < 4; ++mi)
            afrag[mi] = *(const short8*)&sA[(wm + mi * 16 + l15) * APAD + q * 8];
#pragma unroll
        for (int ni = 0; ni < 4; ++ni) {
            const int row = wn + ni * 16 + l15;
            const int col = (q * 4) ^ (((row >> 3) & 3) << 2);
            bfrag[ni] = *(const short8*)(sX + row * XPAD + col);
        }
#pragma unroll
        for (int mi = 0; mi < 4; ++mi)
#pragma unroll
            for (int ni = 0; ni < 4; ++ni)
                acc[mi][ni] = __builtin_amdgcn_mfma_f32_16x16x32_bf16(
                    afrag[mi], bfrag[ni], acc[mi][ni], 0, 0, 0);
    }
#pragma unroll
    for (int mi = 0; mi < 4; ++mi) {
        const int ibase = i0 + wm + mi * 16 + q * 4;
#pragma unroll
        for (int ni = 0; ni < 4; ++ni) {
            const int d = wn + ni * 16 + l15;
#pragma unroll
            for (int r = 0; r < 4; ++r) {
                const int i = ibase + r;
                float v = acc[mi][ni][r] + gcb[(size_t)i * DH + d];
                v = v > 0.f ? v : 0.f;
                out[(((size_t)b * NS + (i & 63)) * NT + (i >> 6)) * DH + d] = v;
            }
        }
    }
}

extern "C" void kernel_launch(void* const* d_in, const int* in_sizes, int n_in,
                              void* d_out, int out_size, void* d_ws, size_t ws_size,
                              hipStream_t stream) {
    const float* h   = (const float*)d_in[0];
    const float* aam = (const float*)d_in[2];
    const float* gcw = (const float*)d_in[3];
    const float* gcb = (const float*)d_in[4];
    float* out = (float*)d_out;

    const size_t A_BYTES   = (size_t)MDIM * KPAD * 2;            // 33.55 MB
    const size_t XT_BYTES  = (size_t)BATCH * DH * KPAD * 2;      // 16.78 MB
    const size_t IDX_BYTES = 64 * 64 * 2;                        // 8 KB
    const size_t NS_BYTES  = 64 * 4;

    if (ws_size >= A_BYTES + XT_BYTES + IDX_BYTES + NS_BYTES) {
        unsigned short* Abf = (unsigned short*)d_ws;
        unsigned short* XTp = (unsigned short*)((char*)d_ws + A_BYTES);
        unsigned short* cid = (unsigned short*)((char*)d_ws + A_BYTES + XT_BYTES);
        int* nsb            = (int*)((char*)d_ws + A_BYTES + XT_BYTES + IDX_BYTES);
        prep<<<dim3(MDIM + BATCH * NT), 256, 0, stream>>>(aam, gcw, h, Abf, XTp, cid, nsb);
        gemm<<<dim3(64 * 8), 256, 0, stream>>>(Abf, XTp, cid, nsb, gcb, out);
    } else {
        gcn_fused<<<dim3((MDIM / TM) * BATCH), 256, 0, stream>>>(h, aam, gcw, gcb, out);
    }
}

// Round 10
// 227.635 us; speedup vs baseline: 1.6325x; 1.1182x over previous
//
#include <hip/hip_runtime.h>

// GCNFast: out[b,s,t,d] = relu( sum_j relu(AA[i%64,j%64]*GCW[i,j]) * X[j,b,d] + GCB[i,d] )
// Sparsity: AA (64x64, ~50% dense) -> per row-group s, support supp(s) in c.
// K reordered kk=c*64+t; A' reordered (UNCOMPACTED) [s*64+tt][c*64+t],
// XT' [b*128+d][c*64+t]. gemm = r4 verbatim (best measured: 63us) except the
// A-tile offset is ka=c*64 (values bit-identical to the compacted variant).
// Round-10: PREP fix. r4-r9 localized the remaining addressable time to prep
//   (~60us inferred vs 25us roofline): the compaction gather did per-thread
//   scalar 4B loads at 256B stride (~64 lines touched per wave instruction).
//   New A-prep: pure per-row 64x64 LDS transpose -- coalesced floatx4 reads,
//   conflict-free padded-column reads (65 = 1 mod 32), coalesced short8
//   writes; rows c not in supp(s) skipped (gemm never reads them).
// Fallback to fused single-kernel path if ws too small.

#define NC 64
#define NS 64
#define NT 64
#define DH 128
#define BATCH 16
#define MDIM 4096
#define KDIM 4096
#define KPAD 4096
#define TM 128
#define TK 64
#define GBM 64
#define GBN 256
#define GBK 64

typedef __attribute__((ext_vector_type(8))) short short8;
typedef __attribute__((ext_vector_type(4))) short short4v;
typedef __attribute__((ext_vector_type(4))) float floatx4;

__device__ __forceinline__ unsigned short f2bf(float f) {
    union { float f; unsigned int i; } v; v.f = f;
    return (unsigned short)((v.i + 0x7fffu + ((v.i >> 16) & 1u)) >> 16);
}
__device__ __forceinline__ void async16(const void* g, void* l) {
    __builtin_amdgcn_global_load_lds(
        (const __attribute__((address_space(1))) void*)g,
        (__attribute__((address_space(3))) void*)l, 16, 0, 0);
}

// ---- fused prep ----
// blocks [0,4096): A' row r=s*64+tt (orig row i=tt*64+s):
//   A'[r][c*64+t] = relu(GCW[i][t*64+c]) via LDS transpose (float sm[64][65];
//   column reads conflict-free). Rows c not in supp(s) are skipped.
//   tt==0 publishes cidx[s][rank]=c and nsb[s]=|supp(s)|.
// blocks [4096,5120): XT'[b*128+d][c*64+t] = bf16(h[b,c,t,d]) via LDS transpose.
__global__ __launch_bounds__(256)
void prep(const float* __restrict__ aam, const float* __restrict__ gcw,
          const float* __restrict__ hmat,
          unsigned short* __restrict__ Abf, unsigned short* __restrict__ XT,
          unsigned short* __restrict__ cidx, int* __restrict__ nsb)
{
    const int tid = threadIdx.x;
    if ((int)blockIdx.x < MDIM) {
        const int r  = blockIdx.x;
        const int s  = r >> 6;
        const int tt = r & 63;
        const int i  = tt * 64 + s;
        __shared__ float smf[64 * 65];
        __shared__ unsigned long long smask;
        if (tid < 64) {
            float v = aam[(size_t)s * KDIM + tid];
            unsigned long long m = __ballot(v != 0.f);
            if (tid == 0) smask = m;
            if (tt == 0) {
                int rank = __popcll(m & ((1ull << tid) - 1ull));
                if (v != 0.f) cidx[s * 64 + rank] = (unsigned short)tid;
                if (tid == 0) nsb[s] = (int)__popcll(m);
            }
        }
        // coalesced read of GCW row i -> LDS [t][c] (pad 65)
        const float* gr = gcw + (size_t)i * KDIM;
#pragma unroll
        for (int u = 0; u < 4; ++u) {
            const int idx = u * 1024 + tid * 4;   // t=idx>>6, c=idx&63
            floatx4 v = *(const floatx4*)(gr + idx);
            *(floatx4*)&smf[(idx >> 6) * 65 + (idx & 63)] = v;
        }
        __syncthreads();
        // transposed write: thread owns (c = tid>>2, tchunk = (tid&3)*16)
        const int c  = tid >> 2;
        const int tc = (tid & 3) << 4;
        if ((smask >> c) & 1ull) {
            short8 p0, p1;
#pragma unroll
            for (int e = 0; e < 8; ++e) {
                float v0 = smf[(tc + e) * 65 + c];      v0 = v0 > 0.f ? v0 : 0.f;
                float v1 = smf[(tc + 8 + e) * 65 + c];  v1 = v1 > 0.f ? v1 : 0.f;
                p0[e] = (short)f2bf(v0);
                p1[e] = (short)f2bf(v1);
            }
            unsigned short* dst = Abf + (size_t)r * KPAD + c * 64 + tc;
            *(short8*)dst       = p0;
            *(short8*)(dst + 8) = p1;
        }
    } else {
        const int blk = blockIdx.x - MDIM;
        const int b = blk >> 6;
        const int c = blk & 63;
        __shared__ unsigned short sx[64][136];
        const float* hp = hmat + (((size_t)b * NC + c) * NT) * DH;
#pragma unroll
        for (int u = 0; u < 8; ++u) {
            const int idx = u * 1024 + tid * 4;   // float idx in [64t][128d]
            const int t = idx >> 7;
            const int d = idx & 127;
            floatx4 v = *(const floatx4*)(hp + idx);
            short4v p;
#pragma unroll
            for (int e = 0; e < 4; ++e) p[e] = (short)f2bf(v[e]);
            *(short4v*)&sx[t][d] = p;
        }
        __syncthreads();
        const int d  = tid >> 1;
        const int th = (tid & 1) * 32;
        unsigned short* dst = XT + ((size_t)(b * DH + d)) * KPAD + c * 64 + th;
#pragma unroll
        for (int u2 = 0; u2 < 4; ++u2) {
            short8 p;
#pragma unroll
            for (int e = 0; e < 8; ++e)
                p[e] = (short)sx[th + u2 * 8 + e][d];
            *(short8*)(dst + u2 * 8) = p;
        }
    }
}

// ---- GEMM: per-s tile C[64, 256], K over ns[s] nonzero c-tiles (r4 verbatim,
//      except A-tile offset ka = c*64 to match the uncompacted A' layout) ----
__global__ __launch_bounds__(256, 2)
void gemm(const unsigned short* __restrict__ Abf,
          const unsigned short* __restrict__ XT,
          const unsigned short* __restrict__ cidx,
          const int* __restrict__ nsb,
          const float* __restrict__ gcb,
          float* __restrict__ out)
{
    __shared__ short lds[2][(GBM + GBN) * GBK];   // 2 x 40 KB = 80 KB

    const int tid = threadIdx.x;
    const int bid = blockIdx.x;
    const int np = bid & 7;        // n-panel -> one per XCD (XT' panel 2MB L2-fits)
    const int s  = bid >> 3;       // row-group 0..63
    const int n0 = np * GBN;

    const int lane = tid & 63;
    const int w    = tid >> 6;     // 0..3
    const int wn   = w * 64;
    const int l15  = lane & 15;
    const int q    = lane >> 4;
    const int srow = lane >> 3;
    const int swz  = ((lane & 7) ^ srow) << 3;   // swizzled k-chunk (elements)

    const int nt = nsb[s];                        // K-tiles = |supp(s)|
    const int cl = (int)cidx[s * 64 + lane];      // lane t holds c(t) (t<nt valid)

    const unsigned short* Ab = Abf + (size_t)(s * 64) * KPAD + swz;
    const unsigned short* Xb = XT  + (size_t)n0 * KPAD + swz;

    floatx4 acc[4][4];
#pragma unroll
    for (int mi = 0; mi < 4; ++mi)
#pragma unroll
        for (int ni = 0; ni < 4; ++ni)
            acc[mi][ni] = (floatx4){0.f, 0.f, 0.f, 0.f};

    // 10 global_load_lds per wave per tile (2 A-groups + 8 X-groups)
    auto stage = [&](int t, int b) {
        short* dst = lds[b];
        const int c = __shfl(cl, t);
        const size_t ka = (size_t)c * GBK;   // A' reordered k-offset (uncompacted)
        const size_t kx = (size_t)c * GBK;   // XT' reordered k-offset
        async16(Ab + (size_t)(w * 8 + srow) * KPAD + ka,       dst + (w * 8) * GBK);
        async16(Ab + (size_t)((w + 4) * 8 + srow) * KPAD + ka, dst + ((w + 4) * 8) * GBK);
#pragma unroll
        for (int g = 0; g < 8; ++g) {
            const int rr = w * 64 + g * 8;
            async16(Xb + (size_t)(rr + srow) * KPAD + kx, dst + (GBM + rr) * GBK);
        }
    };

    auto compute = [&](int b) {
        const short* sA = lds[b];
        const short* sX = lds[b] + GBM * GBK;
#pragma unroll
        for (int h2 = 0; h2 < 2; ++h2) {
            const int co = ((h2 * 4 + q) ^ (l15 & 7)) << 3;
            short8 af[4], xf[4];
#pragma unroll
            for (int mi = 0; mi < 4; ++mi)
                af[mi] = *(const short8*)&sA[(mi * 16 + l15) * GBK + co];
#pragma unroll
            for (int ni = 0; ni < 4; ++ni)
                xf[ni] = *(const short8*)&sX[(wn + ni * 16 + l15) * GBK + co];
            __builtin_amdgcn_s_setprio(1);
#pragma unroll
            for (int mi = 0; mi < 4; ++mi)
#pragma unroll
                for (int ni = 0; ni < 4; ++ni)
                    acc[mi][ni] = __builtin_amdgcn_mfma_f32_16x16x32_bf16(
                        af[mi], xf[ni], acc[mi][ni], 0, 0, 0);
            __builtin_amdgcn_s_setprio(0);
        }
    };

    if (nt > 0) stage(0, 0);
    if (nt > 1) stage(1, 1);
    for (int t = 0; t < nt - 1; ++t) {
        // t's 10 loads retired; (t+1)'s 10 stay in flight
        asm volatile("s_waitcnt vmcnt(10)" ::: "memory");
        __builtin_amdgcn_s_barrier();
        compute(t & 1);
        __builtin_amdgcn_s_barrier();
        if (t + 2 < nt) stage(t + 2, t & 1);
    }
    if (nt > 0) {
        asm volatile("s_waitcnt vmcnt(0)" ::: "memory");
        __builtin_amdgcn_s_barrier();
        compute((nt - 1) & 1);
    }

    // epilogue: row-in-tile tt -> original i = tt*64 + s; out[b, s, tt, d]
#pragma unroll
    for (int mi = 0; mi < 4; ++mi) {
        const int tt0 = mi * 16 + q * 4;
#pragma unroll
        for (int ni = 0; ni < 4; ++ni) {
            const int n  = n0 + wn + ni * 16 + l15;
            const int bb = n >> 7;
            const int d  = n & 127;
#pragma unroll
            for (int r = 0; r < 4; ++r) {
                const int tt = tt0 + r;
                const int i  = tt * 64 + s;
                float v = acc[mi][ni][r] + gcb[(size_t)i * DH + d];
                v = v > 0.f ? v : 0.f;
                out[(((size_t)bb * NS + s) * NT + tt) * DH + d] = v;
            }
        }
    }
}

// ---- fallback: fused kernel (used only if ws too small) ----
#define APAD 40
#define XPAD 20
__global__ __launch_bounds__(256, 2)
void gcn_fused(const float* __restrict__ hmat, const float* __restrict__ aam,
               const float* __restrict__ gcw, const float* __restrict__ gcb,
               float* __restrict__ out)
{
    __shared__ short sA[TM * APAD];
    __shared__ unsigned int sX[DH * XPAD];
    const int tid = threadIdx.x;
    const int bid = blockIdx.x;
    const int mp  = (bid & 7) * 4 + (bid >> 7);
    const int b   = (bid >> 3) & 15;
    const int i0  = mp * TM;
    const int lane = tid & 63;
    const int wm = ((tid >> 6) >> 1) * 64;
    const int wn = ((tid >> 6) & 1) * 64;
    const int l15 = lane & 15;
    const int q   = lane >> 4;
    floatx4 acc[4][4];
#pragma unroll
    for (int mi = 0; mi < 4; ++mi)
#pragma unroll
        for (int ni = 0; ni < 4; ++ni) acc[mi][ni] = (floatx4){0.f,0.f,0.f,0.f};
    const int ar = tid >> 2, ac = (tid & 3) << 3;
    const int kp = tid >> 4, dg = (tid & 15) << 3;
    const int wkey = (tid & 3) << 2;
    for (int k0 = 0; k0 < KDIM; k0 += 32) {
        const size_t ga0 = (size_t)(i0 + ar) * KDIM + (k0 + ac);
        const size_t ga1 = ga0 + (size_t)64 * KDIM;
        floatx4 aa0a = *(const floatx4*)(aam + ga0), aa0b = *(const floatx4*)(aam + ga0 + 4);
        floatx4 ww0a = *(const floatx4*)(gcw + ga0), ww0b = *(const floatx4*)(gcw + ga0 + 4);
        floatx4 aa1a = *(const floatx4*)(aam + ga1), aa1b = *(const floatx4*)(aam + ga1 + 4);
        floatx4 ww1a = *(const floatx4*)(gcw + ga1), ww1b = *(const floatx4*)(gcw + ga1 + 4);
        const int jj = k0 + 2 * kp, tt = jj >> 6, cc = jj & 63;
        const size_t gx0 = ((size_t)(b * NC + cc) * NT + tt) * DH + dg;
        const size_t gx1 = gx0 + (size_t)NT * DH;
        floatx4 x0a = *(const floatx4*)(hmat + gx0), x0b = *(const floatx4*)(hmat + gx0 + 4);
        floatx4 x1a = *(const floatx4*)(hmat + gx1), x1b = *(const floatx4*)(hmat + gx1 + 4);
        __syncthreads();
        short8 p0, p1;
#pragma unroll
        for (int e = 0; e < 4; ++e) {
            float v0 = aa0a[e]*ww0a[e]; v0 = v0>0.f?v0:0.f;
            float v1 = aa0b[e]*ww0b[e]; v1 = v1>0.f?v1:0.f;
            float v2 = aa1a[e]*ww1a[e]; v2 = v2>0.f?v2:0.f;
            float v3 = aa1b[e]*ww1b[e]; v3 = v3>0.f?v3:0.f;
            p0[e] = (short)f2bf(v0); p0[e+4] = (short)f2bf(v1);
            p1[e] = (short)f2bf(v2); p1[e+4] = (short)f2bf(v3);
        }
        *(short8*)&sA[ar * APAD + ac] = p0;
        *(short8*)&sA[(ar + 64) * APAD + ac] = p1;
#pragma unroll
        for (int e = 0; e < 4; ++e) {
            unsigned int pka = (unsigned int)f2bf(x0a[e]) | ((unsigned int)f2bf(x1a[e]) << 16);
            unsigned int pkb = (unsigned int)f2bf(x0b[e]) | ((unsigned int)f2bf(x1b[e]) << 16);
            sX[(dg + e) * XPAD + (kp ^ wkey)] = pka;
            sX[(dg + e + 4) * XPAD + (kp ^ wkey)] = pkb;
        }
        __syncthreads();
        short8 afrag[4], bfrag[4];
#pragma unroll
        for (int mi = 0; mi < 4; ++mi)
            afrag[mi] = *(const short8*)&sA[(wm + mi * 16 + l15) * APAD + q * 8];
#pragma unroll
        for (int ni = 0; ni < 4; ++ni) {
            const int row = wn + ni * 16 + l15;
            const int col = (q * 4) ^ (((row >> 3) & 3) << 2);
            bfrag[ni] = *(const short8*)(sX + row * XPAD + col);
        }
#pragma unroll
        for (int mi = 0; mi < 4; ++mi)
#pragma unroll
            for (int ni = 0; ni < 4; ++ni)
                acc[mi][ni] = __builtin_amdgcn_mfma_f32_16x16x32_bf16(
                    afrag[mi], bfrag[ni], acc[mi][ni], 0, 0, 0);
    }
#pragma unroll
    for (int mi = 0; mi < 4; ++mi) {
        const int ibase = i0 + wm + mi * 16 + q * 4;
#pragma unroll
        for (int ni = 0; ni < 4; ++ni) {
            const int d = wn + ni * 16 + l15;
#pragma unroll
            for (int r = 0; r < 4; ++r) {
                const int i = ibase + r;
                float v = acc[mi][ni][r] + gcb[(size_t)i * DH + d];
                v = v > 0.f ? v : 0.f;
                out[(((size_t)b * NS + (i & 63)) * NT + (i >> 6)) * DH + d] = v;
            }
        }
    }
}

extern "C" void kernel_launch(void* const* d_in, const int* in_sizes, int n_in,
                              void* d_out, int out_size, void* d_ws, size_t ws_size,
                              hipStream_t stream) {
    const float* h   = (const float*)d_in[0];
    const float* aam = (const float*)d_in[2];
    const float* gcw = (const float*)d_in[3];
    const float* gcb = (const float*)d_in[4];
    float* out = (float*)d_out;

    const size_t A_BYTES   = (size_t)MDIM * KPAD * 2;            // 33.55 MB
    const size_t XT_BYTES  = (size_t)BATCH * DH * KPAD * 2;      // 16.78 MB
    const size_t IDX_BYTES = 64 * 64 * 2;                        // 8 KB
    const size_t NS_BYTES  = 64 * 4;

    if (ws_size >= A_BYTES + XT_BYTES + IDX_BYTES + NS_BYTES) {
        unsigned short* Abf = (unsigned short*)d_ws;
        unsigned short* XTp = (unsigned short*)((char*)d_ws + A_BYTES);
        unsigned short* cid = (unsigned short*)((char*)d_ws + A_BYTES + XT_BYTES);
        int* nsb            = (int*)((char*)d_ws + A_BYTES + XT_BYTES + IDX_BYTES);
        prep<<<dim3(MDIM + BATCH * NT), 256, 0, stream>>>(aam, gcw, h, Abf, XTp, cid, nsb);
        gemm<<<dim3(64 * 8), 256, 0, stream>>>(Abf, XTp, cid, nsb, gcb, out);
    } else {
        gcn_fused<<<dim3((MDIM / TM) * BATCH), 256, 0, stream>>>(h, aam, gcw, gcb, out);
    }
}